// Round 6
// baseline (3916.990 us; speedup 1.0000x reference)
//
#include <hip/hip_runtime.h>

// 2-layer LSTM (B=256, T=512, D=64, H=256) + FC(256->4).
// 32 groups x 8 blocks; group = 8 batch elements. Blocks 0-3: layer 0
// (h-quadrant q), blocks 4-7: layer 1. Systolic skew: at super-step s, L0
// computes h0(s), L1 computes h1(s-1).
// Round-6 change: DECOUPLED flag waits (no all-8 barrier).
//   h0 ring-4 slots. L0 waits: L0 peers >= s, L1 >= s-2 (slot-overwrite guard).
//   L1 waits: L0 >= s (normally already satisfied -- L0 runs ahead), L1 peers >= s.
//   h1 stays ring-2. Flags = completed-superstep count, relaxed agent atomics.
// Weights: 16 named u32x8 ext-vectors per thread (packed fp16, register-resident).
// Inner dot loops use 4 accumulator chains (fdot2 dep-latency hiding).

#define TT 512
#define HH 256
#define DD 64

typedef __attribute__((ext_vector_type(2))) _Float16 h2t;
typedef __attribute__((ext_vector_type(8))) unsigned u8v;
typedef unsigned long long u64;

__device__ __forceinline__ h2t f2h2(float f) { return __builtin_bit_cast(h2t, f); }
__device__ __forceinline__ h2t u2h2(unsigned u) { return __builtin_bit_cast(h2t, u); }
__device__ __forceinline__ unsigned pkh(float x, float y) {
    h2t h; h.x = (_Float16)x; h.y = (_Float16)y;
    return __builtin_bit_cast(unsigned, h);
}
__device__ __forceinline__ float sigf(float x) { return 1.f / (1.f + __expf(-x)); }
__device__ __forceinline__ float tanhf_(float x) {
    float e = __expf(2.f * x);
    return 1.f - 2.f / (e + 1.f);   // safe at +/-inf
}

// 16 consecutive fp32 -> one u8v of 8 packed half2
__device__ __forceinline__ u8v ldw16(const float* p) {
    const float4* q = reinterpret_cast<const float4*>(p);
    float4 A = q[0], B = q[1], C = q[2], D = q[3];
    u8v r;
    r.s0 = pkh(A.x, A.y); r.s1 = pkh(A.z, A.w);
    r.s2 = pkh(B.x, B.y); r.s3 = pkh(B.z, B.w);
    r.s4 = pkh(C.x, C.y); r.s5 = pkh(C.z, C.w);
    r.s6 = pkh(D.x, D.y); r.s7 = pkh(D.z, D.w);
    return r;
}

// 16 MACs: u8v weights vs 16 broadcast halves (two float4 = 8 packed half2)
__device__ __forceinline__ float dotu8(u8v w, float4 a, float4 b, float acc) {
    acc = __builtin_amdgcn_fdot2(f2h2(a.x), u2h2(w.s0), acc, false);
    acc = __builtin_amdgcn_fdot2(f2h2(a.y), u2h2(w.s1), acc, false);
    acc = __builtin_amdgcn_fdot2(f2h2(a.z), u2h2(w.s2), acc, false);
    acc = __builtin_amdgcn_fdot2(f2h2(a.w), u2h2(w.s3), acc, false);
    acc = __builtin_amdgcn_fdot2(f2h2(b.x), u2h2(w.s4), acc, false);
    acc = __builtin_amdgcn_fdot2(f2h2(b.y), u2h2(w.s5), acc, false);
    acc = __builtin_amdgcn_fdot2(f2h2(b.z), u2h2(w.s6), acc, false);
    acc = __builtin_amdgcn_fdot2(f2h2(b.w), u2h2(w.s7), acc, false);
    return acc;
}

__device__ __forceinline__ unsigned ldflag(const unsigned* p) {
    return __hip_atomic_load(p, __ATOMIC_RELAXED, __HIP_MEMORY_SCOPE_AGENT);
}
__device__ __forceinline__ u64 ld64(const u64* p) {
    return __hip_atomic_load(p, __ATOMIC_RELAXED, __HIP_MEMORY_SCOPE_AGENT);
}

__global__ __launch_bounds__(512, 2) void lstm_persist(
    const float* __restrict__ x,
    const float* __restrict__ Wih0, const float* __restrict__ Whh0,
    const float* __restrict__ bih0, const float* __restrict__ bhh0,
    const float* __restrict__ Wih1, const float* __restrict__ Whh1,
    const float* __restrict__ bih1, const float* __restrict__ bhh1,
    const float* __restrict__ fcW, const float* __restrict__ fcb,
    float* __restrict__ out,
    unsigned short* h0buf, unsigned short* h1buf, unsigned* counters)
{
    __shared__ __align__(16) unsigned short sh0[8][HH];   // 4 KB  h0(s-1)
    __shared__ __align__(16) unsigned short sh1[8][HH];   // 4 KB  h1(s-2)
    __shared__ __align__(16) unsigned short sx[8][DD];    // 1 KB  x(s) fp16
    __shared__ __align__(16) float part[2][8][256];       // 16 KB partials

    const int tid   = threadIdx.x;
    const int g     = blockIdx.x >> 3;
    const int role  = blockIdx.x & 7;
    const bool isL1 = role >= 4;
    const int q     = isL1 ? role - 4 : role;
    const int batch0 = g * 8;
    unsigned* flags = counters + (size_t)g * 16;   // 8 u32 flags, 64B padded

    const int r  = tid & 255;     // local gate row
    const int kh = tid >> 8;      // k-split half
    const int gq = r >> 6;        // gate 0..3 (i,f,g,o)
    const int ii = r & 63;        // h-index within quadrant
    const int R  = 256 * gq + 64 * q + ii;   // global gate row

    // ---- weights: 16 named u8v (SSA, constant extracts only) ----
    u8v w0 = {}, w1 = {}, w2 = {}, w3 = {}, w4 = {}, w5 = {}, w6 = {}, w7 = {};
    u8v w8 = {}, w9 = {}, w10 = {}, w11 = {}, w12 = {}, w13 = {}, w14 = {}, w15 = {};
    if (isL1) {
        const float* row = (kh ? Whh1 : Wih1) + (size_t)R * HH;
        w0  = ldw16(row +   0); w1  = ldw16(row +  16);
        w2  = ldw16(row +  32); w3  = ldw16(row +  48);
        w4  = ldw16(row +  64); w5  = ldw16(row +  80);
        w6  = ldw16(row +  96); w7  = ldw16(row + 112);
        w8  = ldw16(row + 128); w9  = ldw16(row + 144);
        w10 = ldw16(row + 160); w11 = ldw16(row + 176);
        w12 = ldw16(row + 192); w13 = ldw16(row + 208);
        w14 = ldw16(row + 224); w15 = ldw16(row + 240);
    } else if (kh == 0) {
        const float* ra = Wih0 + (size_t)R * DD;       // x part, 64 halves
        w0 = ldw16(ra); w1 = ldw16(ra + 16); w2 = ldw16(ra + 32); w3 = ldw16(ra + 48);
        const float* rb = Whh0 + (size_t)R * HH;       // h0[0:64]
        w4 = ldw16(rb); w5 = ldw16(rb + 16); w6 = ldw16(rb + 32); w7 = ldw16(rb + 48);
    } else {
        const float* rb = Whh0 + (size_t)R * HH + 64;  // h0[64:256]
        w0  = ldw16(rb +   0); w1  = ldw16(rb +  16);
        w2  = ldw16(rb +  32); w3  = ldw16(rb +  48);
        w4  = ldw16(rb +  64); w5  = ldw16(rb +  80);
        w6  = ldw16(rb +  96); w7  = ldw16(rb + 112);
        w8  = ldw16(rb + 128); w9  = ldw16(rb + 144);
        w10 = ldw16(rb + 160); w11 = ldw16(rb + 176);
    }

    // ---- activation duty: thread (i2 = lane, j2 = wave) ----
    const int i2 = tid & 63, j2 = tid >> 6;
    const float* bA = isL1 ? bih1 : bih0;
    const float* bB = isL1 ? bhh1 : bhh0;
    const float bz0 = bA[0 * 256 + 64 * q + i2] + bB[0 * 256 + 64 * q + i2];
    const float bz1 = bA[1 * 256 + 64 * q + i2] + bB[1 * 256 + 64 * q + i2];
    const float bz2 = bA[2 * 256 + 64 * q + i2] + bB[2 * 256 + 64 * q + i2];
    const float bz3 = bA[3 * 256 + 64 * q + i2] + bB[3 * 256 + 64 * q + i2];
    float cst = 0.f;

    // u64-unit strides: slot = 16384 u64 (131072 B), batch = 64 u64 (512 B)
    const u64* h0u = reinterpret_cast<const u64*>(h0buf);
    const u64* h1u = reinterpret_cast<const u64*>(h1buf);

    for (int s = 0; s <= TT; ++s) {
        const bool active = isL1 ? (s >= 1) : (s < TT);

        // prefetch x(s) into regs (no flag dependency)
        float4 xp;
        const bool doX = (!isL1) && (s < TT) && (tid >= 256) && (tid < 384);
        if (doX) {
            int t2 = tid - 256, j = t2 >> 4, c = t2 & 15;
            xp = reinterpret_cast<const float4*>(
                     x + ((size_t)(batch0 + j) * TT + s) * DD)[c];
        }

        // ---- decoupled epoch waits ----
        // L1 (role>=4): all 8 flags >= s  (L0 producers of h0(s-1); L1 peers' h1(s-2))
        // L0 (role<4):  L0 flags >= s (peer h0(s-1)); L1 flags >= s-2
        //               (slot s&3 was read by L1 at superstep s-3 => flag >= s-2)
        if (s > 0 && tid < 8) {
            int tgt = s;
            if (!isL1 && tid >= 4) tgt = s - 2;
            if (tgt > 0) {
                while (ldflag(&flags[tid]) < (unsigned)tgt)
                    __builtin_amdgcn_s_sleep(1);
            }
        }
        __syncthreads();

        // ---- stage h (+x) into LDS ----
        if (active) {
            // sh0 <- h0(s-1), ring-4 slot (s-1)&3
            reinterpret_cast<u64*>(sh0)[tid] =
                ld64(h0u + (size_t)((s - 1) & 3) * 16384 + batch0 * 64 + tid);
            if (isL1) {  // sh1 <- h1(s-2), ring-2 slot (s-2)&1 == s&1
                reinterpret_cast<u64*>(sh1)[tid] =
                    ld64(h1u + (size_t)(s & 1) * 16384 + batch0 * 64 + tid);
            } else if (doX) {
                int t2 = tid - 256, j = t2 >> 4, c = t2 & 15;
                unsigned* dst = reinterpret_cast<unsigned*>(&sx[j][0]);
                dst[2 * c] = pkh(xp.x, xp.y); dst[2 * c + 1] = pkh(xp.z, xp.w);
            }
        }
        __syncthreads();

        // ---- partial gate dots -> part[kh][j][r]  (4 accumulator chains) ----
        if (active) {
            if (isL1) {
                const float4* hb = reinterpret_cast<const float4*>(kh ? &sh1[0][0] : &sh0[0][0]);
#pragma unroll 2
                for (int j = 0; j < 8; ++j) {
                    const float4* hj = hb + j * 32;
                    float a0 = 0.f, a1 = 0.f, a2 = 0.f, a3 = 0.f;
                    a0 = dotu8(w0,  hj[0],  hj[1],  a0); a1 = dotu8(w1,  hj[2],  hj[3],  a1);
                    a2 = dotu8(w2,  hj[4],  hj[5],  a2); a3 = dotu8(w3,  hj[6],  hj[7],  a3);
                    a0 = dotu8(w4,  hj[8],  hj[9],  a0); a1 = dotu8(w5,  hj[10], hj[11], a1);
                    a2 = dotu8(w6,  hj[12], hj[13], a2); a3 = dotu8(w7,  hj[14], hj[15], a3);
                    a0 = dotu8(w8,  hj[16], hj[17], a0); a1 = dotu8(w9,  hj[18], hj[19], a1);
                    a2 = dotu8(w10, hj[20], hj[21], a2); a3 = dotu8(w11, hj[22], hj[23], a3);
                    a0 = dotu8(w12, hj[24], hj[25], a0); a1 = dotu8(w13, hj[26], hj[27], a1);
                    a2 = dotu8(w14, hj[28], hj[29], a2); a3 = dotu8(w15, hj[30], hj[31], a3);
                    part[kh][j][r] = (a0 + a1) + (a2 + a3);
                }
            } else if (kh == 0) {
#pragma unroll 2
                for (int j = 0; j < 8; ++j) {
                    const float4* xj = reinterpret_cast<const float4*>(&sx[j][0]);
                    const float4* hj = reinterpret_cast<const float4*>(&sh0[j][0]);
                    float a0 = 0.f, a1 = 0.f, a2 = 0.f, a3 = 0.f;
                    a0 = dotu8(w0, xj[0], xj[1], a0); a1 = dotu8(w1, xj[2], xj[3], a1);
                    a2 = dotu8(w2, xj[4], xj[5], a2); a3 = dotu8(w3, xj[6], xj[7], a3);
                    a0 = dotu8(w4, hj[0], hj[1], a0); a1 = dotu8(w5, hj[2], hj[3], a1);
                    a2 = dotu8(w6, hj[4], hj[5], a2); a3 = dotu8(w7, hj[6], hj[7], a3);
                    part[0][j][r] = (a0 + a1) + (a2 + a3);
                }
            } else {
#pragma unroll 2
                for (int j = 0; j < 8; ++j) {
                    const float4* hj = reinterpret_cast<const float4*>(&sh0[j][0]);
                    float a0 = 0.f, a1 = 0.f, a2 = 0.f, a3 = 0.f;
                    a0 = dotu8(w0,  hj[8],  hj[9],  a0); a1 = dotu8(w1,  hj[10], hj[11], a1);
                    a2 = dotu8(w2,  hj[12], hj[13], a2); a3 = dotu8(w3,  hj[14], hj[15], a3);
                    a0 = dotu8(w4,  hj[16], hj[17], a0); a1 = dotu8(w5,  hj[18], hj[19], a1);
                    a2 = dotu8(w6,  hj[20], hj[21], a2); a3 = dotu8(w7,  hj[22], hj[23], a3);
                    a0 = dotu8(w8,  hj[24], hj[25], a0); a1 = dotu8(w9,  hj[26], hj[27], a1);
                    a2 = dotu8(w10, hj[28], hj[29], a2); a3 = dotu8(w11, hj[30], hj[31], a3);
                    part[1][j][r] = (a0 + a1) + (a2 + a3);
                }
            }
        }
        __syncthreads();

        // ---- activation; packed u64 relaxed-agent h store ----
        if (active) {
            float s0 = part[0][j2][(0 << 6) | i2] + part[1][j2][(0 << 6) | i2] + bz0;
            float s1 = part[0][j2][(1 << 6) | i2] + part[1][j2][(1 << 6) | i2] + bz1;
            float s2 = part[0][j2][(2 << 6) | i2] + part[1][j2][(2 << 6) | i2] + bz2;
            float s3 = part[0][j2][(3 << 6) | i2] + part[1][j2][(3 << 6) | i2] + bz3;
            float fi = sigf(s0), ff = sigf(s1), fg = tanhf_(s2), fo = sigf(s3);
            cst = ff * cst + fi * fg;
            float h = fo * tanhf_(cst);

            float hn = __shfl_down(h, 1);
            unsigned lo = pkh(h, hn);
            unsigned hi = __shfl_down(lo, 2);
            if ((i2 & 3) == 0) {
                u64 v = (u64)lo | ((u64)hi << 32);
                unsigned short* base = isL1
                    ? h1buf + (size_t)((s - 1) & 1) * 65536    // h1 ring-2
                    : h0buf + (size_t)(s & 3) * 65536;         // h0 ring-4
                u64* dst = reinterpret_cast<u64*>(base + (size_t)(batch0 + j2) * HH + 64 * q + i2);
                __hip_atomic_store(dst, v, __ATOMIC_RELAXED, __HIP_MEMORY_SCOPE_AGENT);
            }
        }
        asm volatile("s_waitcnt vmcnt(0)" ::: "memory");
        __syncthreads();   // all threads' h stores are at the coherence point

        if (tid == 0)
            __hip_atomic_store(&flags[role], (unsigned)(s + 1),
                               __ATOMIC_RELAXED, __HIP_MEMORY_SCOPE_AGENT);
    }

    // ---- final FC on h1(T-1) (slot 1), by the q==0 L1 block per group ----
    if (isL1 && q == 0) {
        if (tid < 4) {
            while (ldflag(&flags[4 + tid]) < (unsigned)(TT + 1)) __builtin_amdgcn_s_sleep(1);
        }
        __syncthreads();
        reinterpret_cast<u64*>(sh1)[tid] = ld64(h1u + 16384 + batch0 * 64 + tid);
        __syncthreads();

        const int j = tid >> 6, lane = tid & 63;
        const int o = lane >> 4, kk = lane & 15;
        float ssum = 0.f;
#pragma unroll
        for (int m = 0; m < 16; ++m) {
            int k = kk * 16 + m;
            ssum += (float)__builtin_bit_cast(_Float16, sh1[j][k]) * fcW[o * HH + k];
        }
#pragma unroll
        for (int off = 8; off; off >>= 1) ssum += __shfl_down(ssum, off);
        if (kk == 0) out[(batch0 + j) * 4 + o] = ssum + fcb[o];
    }
}

extern "C" void kernel_launch(void* const* d_in, const int* in_sizes, int n_in,
                              void* d_out, int out_size, void* d_ws, size_t ws_size,
                              hipStream_t stream)
{
    (void)in_sizes; (void)n_in; (void)out_size; (void)ws_size;
    const float* x    = (const float*)d_in[0];
    const float* Wih0 = (const float*)d_in[1];
    const float* Whh0 = (const float*)d_in[2];
    const float* bih0 = (const float*)d_in[3];
    const float* bhh0 = (const float*)d_in[4];
    const float* Wih1 = (const float*)d_in[5];
    const float* Whh1 = (const float*)d_in[6];
    const float* bih1 = (const float*)d_in[7];
    const float* bhh1 = (const float*)d_in[8];
    const float* fcW  = (const float*)d_in[9];
    const float* fcb  = (const float*)d_in[10];
    float* out = (float*)d_out;

    // ws: h0buf ring-4 2x...4x256x256 fp16 (512KB) | h1buf ring-2 (256KB) | flags (2KB)
    unsigned short* h0buf = (unsigned short*)d_ws;
    unsigned short* h1buf = (unsigned short*)((char*)d_ws + 524288);
    unsigned*       cnts  = (unsigned*)((char*)d_ws + 786432);

    hipMemsetAsync(d_ws, 0, 788480, stream);

    lstm_persist<<<dim3(256), dim3(512), 0, stream>>>(
        x, Wih0, Whh0, bih0, bhh0, Wih1, Whh1, bih1, bhh1, fcW, fcb, out,
        h0buf, h1buf, cnts);
}

// Round 7
// 1390.990 us; speedup vs baseline: 2.8160x; 2.8160x over previous
//
#include <hip/hip_runtime.h>

// 2-layer LSTM (B=256, T=512, D=64, H=256) + FC(256->4).
// 32 groups x 8 blocks; group = 8 batch elements, pinned to one XCD via
// blockIdx remap (g = bid&31, role = bid>>5 -> all roles of g share bid%8).
// Blocks 0-3: layer 0 (h-quadrant q), 4-7: layer 1. Systolic skew: at
// super-step s, L0 computes h0(s), L1 computes h1(s-1). Round-5 sync
// (all-8 epoch flags, ring-2 h buffers, relaxed agent atomics).
// Round-7: compute via MFMA 16x16x32 f16. Weights register-resident as
// named A-fragments (f16x8 SSA). H staged to LDS as [chunk][row][8] f16
// with row^(chunk&7) XOR swizzle; one ds_read_b128 per B-fragment.
// Layouts (m89/m162-verified family): A row=l&15,k=(l>>4)*8+e;
// B col=l&15 (batch; cols 8-15 zeroed), same k; C col=l&15,row=(l>>4)*4+reg.

#define TT 512
#define HH 256
#define DD 64

typedef __attribute__((ext_vector_type(2))) _Float16 h2t;
typedef __attribute__((ext_vector_type(8))) _Float16 f16x8;
typedef __attribute__((ext_vector_type(4))) float f32x4;
typedef unsigned long long u64;

__device__ __forceinline__ unsigned pkh(float x, float y) {
    h2t h; h.x = (_Float16)x; h.y = (_Float16)y;
    return __builtin_bit_cast(unsigned, h);
}
__device__ __forceinline__ float sigf(float x) { return 1.f / (1.f + __expf(-x)); }
__device__ __forceinline__ float tanhf_(float x) {
    float e = __expf(2.f * x);
    return 1.f - 2.f / (e + 1.f);   // safe at +/-inf
}
// 8 consecutive fp32 -> f16x8
__device__ __forceinline__ f16x8 ld8(const float* p) {
    float4 u = ((const float4*)p)[0];
    float4 v = ((const float4*)p)[1];
    f16x8 r = {(_Float16)u.x, (_Float16)u.y, (_Float16)u.z, (_Float16)u.w,
               (_Float16)v.x, (_Float16)v.y, (_Float16)v.z, (_Float16)v.w};
    return r;
}
__device__ __forceinline__ unsigned ldflag(const unsigned* p) {
    return __hip_atomic_load(p, __ATOMIC_RELAXED, __HIP_MEMORY_SCOPE_AGENT);
}
__device__ __forceinline__ u64 ld64(const u64* p) {
    return __hip_atomic_load(p, __ATOMIC_RELAXED, __HIP_MEMORY_SCOPE_AGENT);
}

// physical half-index in sB for logical (chunk, row): row XOR-swizzled by chunk
__device__ __forceinline__ int phalf(int chunk, int row) {
    return (chunk * 16 + (row ^ (chunk & 7))) * 8;
}

#define DECLA(kt) f16x8 AK##kt##_0 = {}, AK##kt##_1 = {};

__global__ __launch_bounds__(512, 2) void lstm_persist(
    const float* __restrict__ x,
    const float* __restrict__ Wih0, const float* __restrict__ Whh0,
    const float* __restrict__ bih0, const float* __restrict__ bhh0,
    const float* __restrict__ Wih1, const float* __restrict__ Whh1,
    const float* __restrict__ bih1, const float* __restrict__ bhh1,
    const float* __restrict__ fcW, const float* __restrict__ fcb,
    float* __restrict__ out,
    unsigned short* h0buf, unsigned short* h1buf, unsigned* counters)
{
    __shared__ __align__(16) _Float16 sB[8192];   // 16 KB: [64 chunks][16 rows][8]
    __shared__ __align__(16) float part[8][272];  // 8.5 KB gate partials

    const int tid   = threadIdx.x;
    const int g     = blockIdx.x & 31;    // XCD pin: all roles of g share bid%8
    const int role  = blockIdx.x >> 5;
    const bool isL1 = role >= 4;
    const int q     = role & 3;
    const int batch0 = g * 8;
    unsigned* flags = counters + (size_t)g * 16;

    const int lane = tid & 63;
    const int w    = tid >> 6;       // wave = M-tile pair owner; also batch in act
    const int bcol = lane & 15;      // B col (batch; >=8 pad)
    const int kc   = lane >> 4;      // k-chunk within K-tile
    const int koff = kc * 8;

    // ---- A-fragment weight rows: wave w owns local rows [w*32, w*32+32) ----
    const int lr0 = w * 32 + (lane & 15);
    const int lr1 = lr0 + 16;
    const int R0  = 256 * (lr0 >> 6) + 64 * q + (lr0 & 63);
    const int R1  = 256 * (lr1 >> 6) + 64 * q + (lr1 & 63);

    DECLA(0) DECLA(1) DECLA(2) DECLA(3) DECLA(4) DECLA(5) DECLA(6) DECLA(7)
    DECLA(8) DECLA(9) DECLA(10) DECLA(11) DECLA(12) DECLA(13) DECLA(14) DECLA(15)

    if (isL1) {
#define LA1(kt) { const int k_ = (kt) * 32 + koff;                                   \
        AK##kt##_0 = ld8(((k_ < 256) ? Wih1 + (size_t)R0 * 256 + k_                  \
                                     : Whh1 + (size_t)R0 * 256 + (k_ - 256)));       \
        AK##kt##_1 = ld8(((k_ < 256) ? Wih1 + (size_t)R1 * 256 + k_                  \
                                     : Whh1 + (size_t)R1 * 256 + (k_ - 256))); }
        LA1(0) LA1(1) LA1(2) LA1(3) LA1(4) LA1(5) LA1(6) LA1(7)
        LA1(8) LA1(9) LA1(10) LA1(11) LA1(12) LA1(13) LA1(14) LA1(15)
#undef LA1
    } else {
#define LA0(kt) { const int k_ = (kt) * 32 + koff;                                   \
        AK##kt##_0 = ld8(((k_ < 64) ? Wih0 + (size_t)R0 * 64 + k_                    \
                                    : Whh0 + (size_t)R0 * 256 + (k_ - 64)));         \
        AK##kt##_1 = ld8(((k_ < 64) ? Wih0 + (size_t)R1 * 64 + k_                    \
                                    : Whh0 + (size_t)R1 * 256 + (k_ - 64))); }
        LA0(0) LA0(1) LA0(2) LA0(3) LA0(4) LA0(5) LA0(6) LA0(7) LA0(8) LA0(9)
#undef LA0
    }

    // ---- activation duty: thread (lane = h-idx, w = batch) ----
    const float* bA = isL1 ? bih1 : bih0;
    const float* bB = isL1 ? bhh1 : bhh0;
    const float bz0 = bA[0 * 256 + 64 * q + lane] + bB[0 * 256 + 64 * q + lane];
    const float bz1 = bA[1 * 256 + 64 * q + lane] + bB[1 * 256 + 64 * q + lane];
    const float bz2 = bA[2 * 256 + 64 * q + lane] + bB[2 * 256 + 64 * q + lane];
    const float bz3 = bA[3 * 256 + 64 * q + lane] + bB[3 * 256 + 64 * q + lane];
    float cst = 0.f;

    // zero pad rows 8-15 of every chunk (lanes bcol>=8 read zeros forever)
    {
        u64* z = (u64*)sB;
#pragma unroll
        for (int p = 0; p < 2; ++p) {
            int n = tid + p * 512;                  // 1024 pad u64s
            int c = n >> 4, rem = n & 15;
            z[(c * 16 + 8 + (rem >> 1)) * 2 + (rem & 1)] = 0;
        }
    }

    // u64-unit strides: slot = 16384 u64 (131072 B), batch = 64 u64 (512 B)
    const u64* h0u = reinterpret_cast<const u64*>(h0buf);
    const u64* h1u = reinterpret_cast<const u64*>(h1buf);

    for (int s = 0; s <= TT; ++s) {
        const bool active = isL1 ? (s >= 1) : (s < TT);

        // prefetch x(s) into regs (no flag dependency)
        float4 xp;
        const bool doX = (!isL1) && (s < TT) && (tid >= 256) && (tid < 384);
        if (doX) {
            int t2 = tid - 256, j = t2 >> 4, c = t2 & 15;
            xp = reinterpret_cast<const float4*>(
                     x + ((size_t)(batch0 + j) * TT + s) * DD)[c];
        }

        // ---- epoch wait: all 8 blocks finished step s-1 ----
        if (s > 0 && tid < 8) {
            while (ldflag(&flags[tid]) < (unsigned)s) __builtin_amdgcn_s_sleep(1);
        }
        __syncthreads();

        // ---- stage H (+x) into chunked sB ----
        if (active) {
            u64* z = (u64*)sB;
            const int b = tid >> 6, t = tid & 63;   // batch, k-quad (k = 4t)
            // h0(s-1) -> chunks (isL1 ? 0 : 8) + k/8
            u64 hv = ld64(h0u + (size_t)((s + 1) & 1) * 16384 + batch0 * 64 + tid);
            z[phalf((isL1 ? 0 : 8) + (t >> 1), b) / 4 + (t & 1)] = hv;
            if (isL1) {  // h1(s-2) -> chunks 32..63
                u64 hv1 = ld64(h1u + (size_t)(s & 1) * 16384 + batch0 * 64 + tid);
                z[phalf(32 + (t >> 1), b) / 4 + (t & 1)] = hv1;
            } else if (doX) {  // x(s) -> chunks 0..7
                int t2 = tid - 256, j = t2 >> 4, c = t2 & 15;
                u64 v = (u64)pkh(xp.x, xp.y) | ((u64)pkh(xp.z, xp.w) << 32);
                z[phalf(c >> 1, j) / 4 + (c & 1)] = v;
            }
        }
        __syncthreads();

        // ---- MFMA: G = W . Hcat ; two 16-row tiles per wave ----
        if (active) {
            f32x4 Ca = {0.f, 0.f, 0.f, 0.f}, Cb = {0.f, 0.f, 0.f, 0.f};
#define MK(kt) { const int ch_ = (kt) * 4 + kc;                                       \
        const f16x8 Bf = *(const f16x8*)(sB + phalf(ch_, bcol));                      \
        Ca = __builtin_amdgcn_mfma_f32_16x16x32_f16(AK##kt##_0, Bf, Ca, 0, 0, 0);     \
        Cb = __builtin_amdgcn_mfma_f32_16x16x32_f16(AK##kt##_1, Bf, Cb, 0, 0, 0); }
            if (isL1) {
                MK(0) MK(1) MK(2) MK(3) MK(4) MK(5) MK(6) MK(7)
                MK(8) MK(9) MK(10) MK(11) MK(12) MK(13) MK(14) MK(15)
            } else {
                MK(0) MK(1) MK(2) MK(3) MK(4) MK(5) MK(6) MK(7) MK(8) MK(9)
            }
#undef MK
            if (bcol < 8) {   // C: col=batch, rows (lane>>4)*4+reg within tile
                *(f32x4*)&part[bcol][w * 32 + kc * 4]      = Ca;
                *(f32x4*)&part[bcol][w * 32 + 16 + kc * 4] = Cb;
            }
        }
        __syncthreads();

        // ---- activation; packed u64 relaxed-agent h store ----
        if (active) {
            float s0 = part[w][(0 << 6) | lane] + bz0;
            float s1 = part[w][(1 << 6) | lane] + bz1;
            float s2 = part[w][(2 << 6) | lane] + bz2;
            float s3 = part[w][(3 << 6) | lane] + bz3;
            float fi = sigf(s0), ff = sigf(s1), fg = tanhf_(s2), fo = sigf(s3);
            cst = ff * cst + fi * fg;
            float h = fo * tanhf_(cst);

            float hn = __shfl_down(h, 1);
            unsigned lo = pkh(h, hn);
            unsigned hi = __shfl_down(lo, 2);
            if ((lane & 3) == 0) {
                u64 v = (u64)lo | ((u64)hi << 32);
                unsigned short* base = isL1
                    ? h1buf + (size_t)((s - 1) & 1) * 65536
                    : h0buf + (size_t)(s & 1) * 65536;
                u64* dst = reinterpret_cast<u64*>(base + (size_t)(batch0 + w) * HH + 64 * q + lane);
                __hip_atomic_store(dst, v, __ATOMIC_RELAXED, __HIP_MEMORY_SCOPE_AGENT);
            }
        }
        asm volatile("s_waitcnt vmcnt(0)" ::: "memory");
        __syncthreads();   // all threads' h stores are at the coherence point

        if (tid == 0)
            __hip_atomic_store(&flags[role], (unsigned)(s + 1),
                               __ATOMIC_RELAXED, __HIP_MEMORY_SCOPE_AGENT);
    }

    // ---- final FC on h1(T-1) (slot 1), by the q==0 L1 block per group ----
    if (isL1 && q == 0) {
        if (tid < 4) {
            while (ldflag(&flags[4 + tid]) < (unsigned)(TT + 1)) __builtin_amdgcn_s_sleep(1);
        }
        __syncthreads();
        ((u64*)sB)[tid] = ld64(h1u + 16384 + batch0 * 64 + tid);  // flat [b*256+k]
        __syncthreads();

        const int j = tid >> 6, l2 = tid & 63;
        const int o = l2 >> 4, kk = l2 & 15;
        float ssum = 0.f;
#pragma unroll
        for (int m = 0; m < 16; ++m) {
            int k = kk * 16 + m;
            ssum += (float)sB[j * 256 + k] * fcW[o * HH + k];
        }
#pragma unroll
        for (int off = 8; off; off >>= 1) ssum += __shfl_down(ssum, off);
        if (kk == 0) out[(batch0 + j) * 4 + o] = ssum + fcb[o];
    }
}

extern "C" void kernel_launch(void* const* d_in, const int* in_sizes, int n_in,
                              void* d_out, int out_size, void* d_ws, size_t ws_size,
                              hipStream_t stream)
{
    (void)in_sizes; (void)n_in; (void)out_size; (void)ws_size;
    const float* x    = (const float*)d_in[0];
    const float* Wih0 = (const float*)d_in[1];
    const float* Whh0 = (const float*)d_in[2];
    const float* bih0 = (const float*)d_in[3];
    const float* bhh0 = (const float*)d_in[4];
    const float* Wih1 = (const float*)d_in[5];
    const float* Whh1 = (const float*)d_in[6];
    const float* bih1 = (const float*)d_in[7];
    const float* bhh1 = (const float*)d_in[8];
    const float* fcW  = (const float*)d_in[9];
    const float* fcb  = (const float*)d_in[10];
    float* out = (float*)d_out;

    // ws: h0buf ring-2 2x256x256 fp16 (256KB) | h1buf ring-2 (256KB) | flags (2KB)
    unsigned short* h0buf = (unsigned short*)d_ws;
    unsigned short* h1buf = (unsigned short*)((char*)d_ws + 262144);
    unsigned*       cnts  = (unsigned*)((char*)d_ws + 524288);

    hipMemsetAsync(d_ws, 0, 524288 + 2048, stream);

    lstm_persist<<<dim3(256), dim3(512), 0, stream>>>(
        x, Wih0, Whh0, bih0, bhh0, Wih1, Whh1, bih1, bhh1, fcW, fcb, out,
        h0buf, h1buf, cnts);
}

// Round 8
// 1277.966 us; speedup vs baseline: 3.0650x; 1.0884x over previous
//
#include <hip/hip_runtime.h>

// 2-layer LSTM (B=256, T=512, D=64, H=256) + FC(256->4).
// 32 groups x 8 blocks (group pinned to one XCD slot via bid&31); blocks 0-3:
// layer 0 quadrant q, 4-7: layer 1 quadrant q. Systolic skew: iter s computes
// h0(s) on L0 and h1(s-1) on L1.
// Round-8: self-validating packet exchange. h stored as u64 {epoch32|2xf16}
// relaxed-agent atomics into ring-4 buffers; consumers retry-load until the
// embedded epoch matches (1 RTT discovery, no flags/fences on critical path).
// cflag = "staged inputs for step s" (posted s+1 at top of iter s) guards ring
// overwrite with 2-step slack. 2 barriers/step. MFMA 16x16x32 f16, weights as
// named A-fragment SSA values (4Mx2K wave split, 128 VGPR). LDS: 288B chunk
// stride (bank-balanced B reads), part2 padded to 276 (balanced C writes).

#define TT 512
#define HH 256
#define DD 64

typedef __attribute__((ext_vector_type(2))) _Float16 h2t;
typedef __attribute__((ext_vector_type(8))) _Float16 f16x8;
typedef __attribute__((ext_vector_type(4))) float f32x4;
typedef unsigned long long u64;
typedef unsigned u32;

__device__ __forceinline__ u32 pkh(float x, float y) {
    h2t h; h.x = (_Float16)x; h.y = (_Float16)y;
    return __builtin_bit_cast(u32, h);
}
__device__ __forceinline__ float sigf(float x) { return 1.f / (1.f + __expf(-x)); }
__device__ __forceinline__ float tanhf_(float x) {
    float e = __expf(2.f * x);
    return 1.f - 2.f / (e + 1.f);   // safe at +/-inf
}
__device__ __forceinline__ f16x8 ld8(const float* p) {
    float4 u = ((const float4*)p)[0];
    float4 v = ((const float4*)p)[1];
    f16x8 r = {(_Float16)u.x, (_Float16)u.y, (_Float16)u.z, (_Float16)u.w,
               (_Float16)v.x, (_Float16)v.y, (_Float16)v.z, (_Float16)v.w};
    return r;
}
__device__ __forceinline__ u32 ld32(const u32* p) {
    return __hip_atomic_load(p, __ATOMIC_RELAXED, __HIP_MEMORY_SCOPE_AGENT);
}
__device__ __forceinline__ void st32(u32* p, u32 v) {
    __hip_atomic_store(p, v, __ATOMIC_RELAXED, __HIP_MEMORY_SCOPE_AGENT);
}
__device__ __forceinline__ u64 ld64(const u64* p) {
    return __hip_atomic_load(p, __ATOMIC_RELAXED, __HIP_MEMORY_SCOPE_AGENT);
}
__device__ __forceinline__ void st64(u64* p, u64 v) {
    __hip_atomic_store(p, v, __ATOMIC_RELAXED, __HIP_MEMORY_SCOPE_AGENT);
}

__global__ __launch_bounds__(512, 2) void lstm_persist(
    const float* __restrict__ x,
    const float* __restrict__ Wih0, const float* __restrict__ Whh0,
    const float* __restrict__ bih0, const float* __restrict__ bhh0,
    const float* __restrict__ Wih1, const float* __restrict__ Whh1,
    const float* __restrict__ bih1, const float* __restrict__ bhh1,
    const float* __restrict__ fcW, const float* __restrict__ fcb,
    float* __restrict__ out,
    u64* h0ring, u64* h1ring, u32* cflagsA)
{
    __shared__ __align__(16) _Float16 sB[9216];        // 64 chunks x 144 halves (288B stride)
    __shared__ __align__(16) float part2[2][8][276];   // k-split partials, padded

    const int tid  = threadIdx.x;
    const int g    = blockIdx.x & 31;     // all 8 roles of g share bid%8 (XCD slot)
    const int role = blockIdx.x >> 5;
    const bool isL1 = role >= 4;
    const int q = role & 3;
    const int batch0 = g * 8;
    u64* ring0 = h0ring + (size_t)g * 4096;   // [slot4][q4][j8][m32]
    u64* ring1 = h1ring + (size_t)g * 4096;
    u32* cflag = cflagsA + (size_t)g * 16;

    const int lane = tid & 63, w = tid >> 6;   // w: MFMA wave id / act batch
    const int mw = w & 3, kh = w >> 2;         // M-group (=gate), K-half
    const int bcol = lane & 15, kc = lane >> 4;

    // ---- A-fragment rows: wave mw owns gate mw; tiles ti=0..3 (16 rows each)
    const int R0 = mw * 256 + 64 * q + (lane & 15);
    const int R1 = R0 + 16, R2 = R0 + 32, R3 = R0 + 48;

#define DECL_TI(ti) f16x8 A##ti##_0={},A##ti##_1={},A##ti##_2={},A##ti##_3={}, \
                          A##ti##_4={},A##ti##_5={},A##ti##_6={},A##ti##_7={};
    DECL_TI(0) DECL_TI(1) DECL_TI(2) DECL_TI(3)
#undef DECL_TI

    if (isL1) {
#define LDA1(ti,j) { int k_ = (kh*8+(j))*32 + kc*8;                          \
        A##ti##_##j = ld8(k_ < 256 ? Wih1 + (size_t)R##ti*256 + k_           \
                                   : Whh1 + (size_t)R##ti*256 + (k_-256)); }
#define LDA1T(ti) LDA1(ti,0) LDA1(ti,1) LDA1(ti,2) LDA1(ti,3) \
                  LDA1(ti,4) LDA1(ti,5) LDA1(ti,6) LDA1(ti,7)
        LDA1T(0) LDA1T(1) LDA1T(2) LDA1T(3)
#undef LDA1T
#undef LDA1
    } else {
#define LDA0(ti,j) { int k_ = (kh*5+(j))*32 + kc*8;                          \
        A##ti##_##j = ld8(k_ < 64 ? Wih0 + (size_t)R##ti*64 + k_             \
                                  : Whh0 + (size_t)R##ti*256 + (k_-64)); }
#define LDA0T(ti) LDA0(ti,0) LDA0(ti,1) LDA0(ti,2) LDA0(ti,3) LDA0(ti,4)
        LDA0T(0) LDA0T(1) LDA0T(2) LDA0T(3)
#undef LDA0T
#undef LDA0
    }

    // ---- activation duty: thread (lane = h-idx in quadrant, w = batch) ----
    const float* bA = isL1 ? bih1 : bih0;
    const float* bB = isL1 ? bhh1 : bhh0;
    const float bz0 = bA[      64*q + lane] + bB[      64*q + lane];
    const float bz1 = bA[256 + 64*q + lane] + bB[256 + 64*q + lane];
    const float bz2 = bA[512 + 64*q + lane] + bB[512 + 64*q + lane];
    const float bz3 = bA[768 + 64*q + lane] + bB[768 + 64*q + lane];
    float cst = 0.f;

    u32* const sBu = (u32*)sB;
    // zero sB (rows 8-15 of every chunk must stay zero: batch pad)
    for (int i = tid; i < 4608; i += 512) sBu[i] = 0;

    // ---- staging: load packets for step snext, retry on embedded epoch ----
    auto stage_next = [&](int snext) {
        const bool st0 = (!isL1) && (snext < TT);
        const bool st1 = isL1 && (snext >= 1) && (snext <= TT);
        if (!(st0 || st1)) return;
        {   // h0(snext-1): slot (snext-1)&3, epoch snext
            const int slot = (snext - 1) & 3;
            const u32 e0 = (u32)snext;
            const int base = isL1 ? 0 : 8;
#pragma unroll
            for (int pp = 0; pp < 2; ++pp) {
                int p = tid + pp * 512;
                int j = p >> 7, n = p & 127;
                const u64* a = ring0 + slot * 1024 + (n >> 5) * 256 + j * 32 + (n & 31);
                u64 v;
                do { v = ld64(a); } while ((u32)(v >> 32) != e0);
                sBu[(base + (n >> 2)) * 72 + j * 4 + (n & 3)] = (u32)v;
            }
        }
        if (isL1) {  // h1(snext-2): slot (snext+2)&3, epoch (snext>=2 ? snext : 0)
            const int slot = (snext + 2) & 3;
            const u32 e1 = (snext >= 2) ? (u32)snext : 0u;
#pragma unroll
            for (int pp = 0; pp < 2; ++pp) {
                int p = tid + pp * 512;
                int j = p >> 7, n = p & 127;
                const u64* a = ring1 + slot * 1024 + (n >> 5) * 256 + j * 32 + (n & 31);
                u64 v;
                do { v = ld64(a); } while ((u32)(v >> 32) != e1);
                sBu[(32 + (n >> 2)) * 72 + j * 4 + (n & 3)] = (u32)v;
            }
        } else if (tid >= 256 && tid < 384) {  // x(snext) -> chunks 0..7
            int t2 = tid - 256, j = t2 >> 4, c = t2 & 15;
            float4 v = ((const float4*)(x + ((size_t)(batch0 + j) * TT + snext) * DD))[c];
            int bidx = (c >> 1) * 72 + j * 4 + (c & 1) * 2;
            sBu[bidx]     = pkh(v.x, v.y);
            sBu[bidx + 1] = pkh(v.z, v.w);
        }
    };
    stage_next(0);   // prologue: h0(-1)=zeros (epoch 0 via memset), x(0)

    for (int s = 0; s <= TT; ++s) {
        __syncthreads();   // staging for step s complete block-wide
        if (tid == 0) st32(&cflag[role], (u32)(s + 1));   // CF: staged step s

        const bool act_ = isL1 ? (s >= 1) : (s < TT);

        // pre-issue ring-guard loads (checked after act; RTT hidden under MFMA)
        u32 cpre = 0xFFFFFFFFu;
        if (act_ && lane < 8) cpre = ld32(&cflag[lane]);

        if (act_) {
            f32x4 C0 = {0,0,0,0}, C1 = {0,0,0,0}, C2 = {0,0,0,0}, C3 = {0,0,0,0};
#define MST(j, ktb) { const f16x8 Bf = *(const f16x8*)(sB + (((ktb)+(j))*4 + kc)*144 + bcol*8); \
            C0 = __builtin_amdgcn_mfma_f32_16x16x32_f16(A0_##j, Bf, C0, 0,0,0); \
            C1 = __builtin_amdgcn_mfma_f32_16x16x32_f16(A1_##j, Bf, C1, 0,0,0); \
            C2 = __builtin_amdgcn_mfma_f32_16x16x32_f16(A2_##j, Bf, C2, 0,0,0); \
            C3 = __builtin_amdgcn_mfma_f32_16x16x32_f16(A3_##j, Bf, C3, 0,0,0); }
            if (isL1) {
                const int ktb = kh * 8;
                MST(0,ktb) MST(1,ktb) MST(2,ktb) MST(3,ktb)
                MST(4,ktb) MST(5,ktb) MST(6,ktb) MST(7,ktb)
            } else {
                const int ktb = kh * 5;
                MST(0,ktb) MST(1,ktb) MST(2,ktb) MST(3,ktb) MST(4,ktb)
            }
#undef MST
            if (bcol < 8) {   // C: col=batch(bcol), row=(kc)*4+reg within tile
                *(f32x4*)&part2[kh][bcol][mw*64 +  0 + kc*4] = C0;
                *(f32x4*)&part2[kh][bcol][mw*64 + 16 + kc*4] = C1;
                *(f32x4*)&part2[kh][bcol][mw*64 + 32 + kc*4] = C2;
                *(f32x4*)&part2[kh][bcol][mw*64 + 48 + kc*4] = C3;
            }
        }
        __syncthreads();   // part2 ready; all sB reads of step s done

        if (act_) {
            float s0 = part2[0][w][      lane] + part2[1][w][      lane] + bz0;
            float s1 = part2[0][w][ 64 + lane] + part2[1][w][ 64 + lane] + bz1;
            float s2 = part2[0][w][128 + lane] + part2[1][w][128 + lane] + bz2;
            float s3 = part2[0][w][192 + lane] + part2[1][w][192 + lane] + bz3;
            float fi = sigf(s0), ff = sigf(s1), fg = tanhf_(s2), fo = sigf(s3);
            cst = ff * cst + fi * fg;
            float h = fo * tanhf_(cst);
            float hn = __shfl_down(h, 1);

            // ring-overwrite guard: all 8 blocks staged step s-2 (slack 2)
            const int tgt = s - 2;
            while (!__all(lane >= 8 || (int)cpre >= tgt)) {
                __builtin_amdgcn_s_sleep(1);
                if (lane < 8) cpre = ld32(&cflag[lane]);
            }
            if (!(lane & 1)) {   // packet: {epoch s+1 | h_odd | h_even}
                u64 v = ((u64)(u32)(s + 1) << 32) | (u64)pkh(h, hn);
                u64* dst = (isL1 ? ring1 + (size_t)((s - 1) & 3) * 1024
                                 : ring0 + (size_t)(s & 3) * 1024)
                           + q * 256 + w * 32 + (lane >> 1);
                st64(dst, v);
            }
        }

        stage_next(s + 1);   // overlaps peers' stores; retry until epochs match
    }

    // ---- final FC on h1(TT-1): slot 3, epoch TT+1; q==0 L1 block per group ----
    if (isL1 && q == 0) {
        const u32 ef = (u32)(TT + 1);
#pragma unroll
        for (int pp = 0; pp < 2; ++pp) {
            int p = tid + pp * 512;
            int j = p >> 7, n = p & 127;
            const u64* a = ring1 + 3 * 1024 + (n >> 5) * 256 + j * 32 + (n & 31);
            u64 v;
            do { v = ld64(a); } while ((u32)(v >> 32) != ef);
            sBu[j * 128 + n] = (u32)v;   // flat [batch][128 u32]
        }
        __syncthreads();
        const int j = tid >> 6, l2 = tid & 63;
        const int o = l2 >> 4, kk = l2 & 15;
        float ssum = 0.f;
#pragma unroll
        for (int m = 0; m < 16; ++m) {
            int k = kk * 16 + m;
            ssum += (float)sB[j * 256 + k] * fcW[o * HH + k];
        }
#pragma unroll
        for (int off = 8; off; off >>= 1) ssum += __shfl_down(ssum, off);
        if (kk == 0) out[(batch0 + j) * 4 + o] = ssum + fcb[o];
    }
}

extern "C" void kernel_launch(void* const* d_in, const int* in_sizes, int n_in,
                              void* d_out, int out_size, void* d_ws, size_t ws_size,
                              hipStream_t stream)
{
    (void)in_sizes; (void)n_in; (void)out_size; (void)ws_size;
    const float* x    = (const float*)d_in[0];
    const float* Wih0 = (const float*)d_in[1];
    const float* Whh0 = (const float*)d_in[2];
    const float* bih0 = (const float*)d_in[3];
    const float* bhh0 = (const float*)d_in[4];
    const float* Wih1 = (const float*)d_in[5];
    const float* Whh1 = (const float*)d_in[6];
    const float* bih1 = (const float*)d_in[7];
    const float* bhh1 = (const float*)d_in[8];
    const float* fcW  = (const float*)d_in[9];
    const float* fcb  = (const float*)d_in[10];
    float* out = (float*)d_out;

    // ws: h0ring 1MB (32 grp x 4 slot x 1024 u64) | h1ring 1MB | cflags 2KB
    u64* h0ring = (u64*)d_ws;
    u64* h1ring = (u64*)((char*)d_ws + 1048576);
    u32* cflags = (u32*)((char*)d_ws + 2097152);

    hipMemsetAsync(d_ws, 0, 2097152 + 2048, stream);   // epoch 0 == h(-1)=0

    lstm_persist<<<dim3(256), dim3(512), 0, stream>>>(
        x, Wih0, Whh0, bih0, bhh0, Wih1, Whh1, bih1, bhh1, fcW, fcb, out,
        h0ring, h1ring, cflags);
}